// Round 11
// baseline (119.516 us; speedup 1.0000x reference)
//
#include <hip/hip_runtime.h>

#define HEADS 12
#define DH 64
#define NB 4
#define NSEQ 2048
#define DIMV 768
#define MTOT (NB*NSEQ)   // 8192

typedef __attribute__((ext_vector_type(8))) short bf16x8;
typedef __attribute__((ext_vector_type(4))) short bf16x4;
typedef __attribute__((ext_vector_type(4))) float f32x4;
typedef __attribute__((ext_vector_type(8))) float f32x8;
typedef __attribute__((ext_vector_type(8))) unsigned short u16x8;
typedef __attribute__((ext_vector_type(4))) unsigned short u16x4;

__device__ __forceinline__ unsigned short f2bf(float f){
  union { float f; unsigned u; } v; v.f = f;
  unsigned r = v.u + 0x7FFFu + ((v.u >> 16) & 1u);
  return (unsigned short)(r >> 16);
}

__device__ __forceinline__ unsigned cvt_pk_bf16(float lo, float hi){
  unsigned r;
  asm("v_cvt_pk_bf16_f32 %0, %1, %2" : "=v"(r) : "v"(lo), "v"(hi));
  return r;
}

// async global->LDS, 16B per lane; LDS dest = wave-uniform base + lane*16
__device__ __forceinline__ void gl16(const void* g, void* l){
  __builtin_amdgcn_global_load_lds(
      (const __attribute__((address_space(1))) unsigned int*)g,
      (__attribute__((address_space(3))) unsigned int*)l, 16, 0, 0);
}

// ---------------- prep: x -> bf16  AND  W -> Wt bf16 [n][k], fused ----------------
__global__ __launch_bounds__(256) void prep_kernel(const float* __restrict__ x,
                                                   const float* __restrict__ Wq,
                                                   const float* __restrict__ Wk,
                                                   const float* __restrict__ Wv,
                                                   const float* __restrict__ Wo,
                                                   unsigned short* __restrict__ xb,
                                                   unsigned short* __restrict__ dstAll){
  __shared__ float t[32][33];
  int bid = blockIdx.x;
  if (bid < 3072){
    int i = (bid * 256 + (int)threadIdx.x) * 8;
    f32x8 v = *(const f32x8*)(x + i);
    u16x8 o;
#pragma unroll
    for (int j = 0; j < 8; j++) o[j] = f2bf(v[j]);
    *(u16x8*)(xb + i) = o;
  } else {
    int wb = bid - 3072;                  // 0..2303
    int w = wb / 576, rem = wb % 576;
    int n0 = (rem / 24) * 32, k0 = (rem % 24) * 32;
    const float* src = (w == 0) ? Wq : (w == 1) ? Wk : (w == 2) ? Wv : Wo;
    unsigned short* dst = dstAll + (size_t)w * DIMV * DIMV;
    int tx = threadIdx.x & 31, ty = threadIdx.x >> 5;   // 32 x 8
#pragma unroll
    for (int i = 0; i < 4; i++){
      int kk = ty + i * 8;
      t[kk][tx] = src[(k0 + kk) * DIMV + n0 + tx];
    }
    __syncthreads();
#pragma unroll
    for (int i = 0; i < 4; i++){
      int nn = ty + i * 8;
      dst[(n0 + nn) * DIMV + k0 + tx] = f2bf(t[tx][nn]);
    }
  }
}

// ---------------- QKV GEMM: C[8192 x 2304] = Xb @ [Wq|Wk|Wv] ----------------
// 128x192x64 tiles (grid 64x12 = 768 = exactly 3 blocks/CU), single-buffered,
// 48 MFMA/wave/iter. 192 | 768 so each n-tile lies in one z.  (round-9 state)
__global__ __launch_bounds__(256, 3) void gemm_qkv_kernel(const unsigned short* __restrict__ Xb,
                                                          const unsigned short* __restrict__ Wts,
                                                          unsigned short* __restrict__ Qb,
                                                          unsigned short* __restrict__ Kb,
                                                          unsigned short* __restrict__ Vt){
  int m0 = blockIdx.x * 128;
  int n2 = blockIdx.y;                   // 0..11
  int z  = n2 >> 2;
  int nb = (n2 & 3) * 192;
  const unsigned short* W = Wts + (size_t)z * DIMV * DIMV;  // Wt[n][k]
  __shared__ __align__(16) unsigned short As[128 * 64];     // 16KB
  __shared__ __align__(16) unsigned short Bs[192 * 64];     // 24KB
  int tid = threadIdx.x;
  int wid = tid >> 6, lane = tid & 63;
  int wr = wid >> 1, wc = wid & 1;
  int q = lane >> 4, rr = lane & 15, m8 = rr & 7;

  f32x4 acc[4][6];
  f32x4 zero = {0.f, 0.f, 0.f, 0.f};
#pragma unroll
  for (int i = 0; i < 4; i++)
#pragma unroll
    for (int j = 0; j < 6; j++) acc[i][j] = zero;

  int aoff[2], boff[2];
#pragma unroll
  for (int kk = 0; kk < 2; kk++){
    int cx = (((kk * 4 + q) ^ m8) << 4);
    aoff[kk] = (wr * 64 + rr) * 128 + cx;
    boff[kk] = (wc * 96 + rr) * 128 + cx;
  }
  // single base pointers; per-load row stride is compile-time (32 rows = 49152B)
  int srow = wid * 8 + (lane >> 3);
  int sjc = ((lane & 7) ^ ((lane >> 3) & 7)) << 3;
  const unsigned short* pA0 = Xb + (size_t)(m0 + srow) * DIMV + sjc;
  const unsigned short* pB0 = W  + (size_t)(nb + srow) * DIMV + sjc;

  auto stage = [&](){
#pragma unroll
    for (int rd = 0; rd < 4; rd++)
      gl16(pA0 + rd * 32 * DIMV, (char*)As + (rd * 4 + wid) * 1024);
#pragma unroll
    for (int i = 0; i < 6; i++)
      gl16(pB0 + i * 32 * DIMV, (char*)Bs + (i * 4 + wid) * 1024);
    pA0 += 64; pB0 += 64;
  };

  for (int kt = 0; kt < DIMV / 64; kt++){
    __syncthreads();
    stage();
    asm volatile("s_waitcnt vmcnt(0)" ::: "memory");
    __syncthreads();
#pragma unroll
    for (int kk = 0; kk < 2; kk++){
      bf16x8 af[4], bfm[6];
#pragma unroll
      for (int mi = 0; mi < 4; mi++)
        af[mi] = *(const bf16x8*)((char*)As + aoff[kk] + mi * 2048);
#pragma unroll
      for (int ni = 0; ni < 6; ni++)
        bfm[ni] = *(const bf16x8*)((char*)Bs + boff[kk] + ni * 2048);
      __builtin_amdgcn_s_setprio(1);
#pragma unroll
      for (int mi = 0; mi < 4; mi++)
#pragma unroll
        for (int ni = 0; ni < 6; ni++)
          acc[mi][ni] = __builtin_amdgcn_mfma_f32_16x16x32_bf16(af[mi], bfm[ni], acc[mi][ni], 0, 0, 0);
      __builtin_amdgcn_s_setprio(0);
    }
  }

  const float QSCALE = 0.125f * 1.4426950408889634f;  // fold softmax scale + log2e into Q
#pragma unroll
  for (int mi = 0; mi < 4; mi++){
#pragma unroll
    for (int ni = 0; ni < 6; ni++){
      int col = nb + wc * 96 + ni * 16 + rr;
      int mrow0 = m0 + wr * 64 + mi * 16 + q * 4;
      f32x4 v = acc[mi][ni];
      if (z == 0){
#pragma unroll
        for (int r = 0; r < 4; r++)
          Qb[(size_t)(mrow0 + r) * DIMV + col] = f2bf(v[r] * QSCALE);
      } else if (z == 1){
#pragma unroll
        for (int r = 0; r < 4; r++)
          Kb[(size_t)(mrow0 + r) * DIMV + col] = f2bf(v[r]);
      } else {
        int b = mrow0 >> 11;
        int n = mrow0 & 2047;
        // kv-permutation within each 32-chunk: slot = 8g+j <-> kv = 4g+j (+16 for j>=4)
        int np = (n & ~31) | (((n >> 2) & 3) << 3) | ((n & 16) >> 2);
        int h = col >> 6, d = col & 63;
        u16x4 pk;
#pragma unroll
        for (int r = 0; r < 4; r++) pk[r] = f2bf(v[r]);
        *(u16x4*)(&Vt[(((size_t)b * HEADS + h) * DH + d) * NSEQ + np]) = pk;
      }
    }
  }
}

// ---------------- flash attention, swapped-QK^T, max-free log2 softmax ----------------
// 4 waves x 32 q-rows, KV tile 64. NEW: 3-buffer K/V pipeline with raw s_barrier +
// counted vmcnt(4) -- loads stay in flight across barriers (T4), staged one full
// compute-phase ahead. kv-permuted V (single-b128 PV reads), XCD head-locality,
// l on the matrix pipe via all-ones A-fragment.
__global__ __launch_bounds__(256, 3) void attn_kernel(const unsigned short* __restrict__ Qb,
                                                      const unsigned short* __restrict__ Kb,
                                                      const unsigned short* __restrict__ Vt,
                                                      unsigned short* __restrict__ Ob){
  int bid = blockIdx.x;                  // 768 = 8 xcd * 6 heads * 16 qx
  int xcd = bid & 7, wi = bid >> 3;      // wi in [0,96)
  int bh = xcd * 6 + (wi >> 4);
  int qx = wi & 15;
  int b = bh / HEADS, h = bh % HEADS;
  int tid = threadIdx.x, w = tid >> 6, lane = tid & 63;
  int lq = lane & 15, g = lane >> 4, m = lq & 7;

  __shared__ __align__(16) unsigned short Ks[3][64 * 64];  // [kv][d], swizzled, 24KB
  __shared__ __align__(16) unsigned short Vs[3][64 * 64];  // [d][kv-perm], swizzled, 24KB

  int qb = qx * 128 + w * 32;

  // Q^T B-fragments: lane holds Q[q=lq][d = ch*32 + 8g..+8]
  bf16x8 qf[2][2];
#pragma unroll
  for (int qt = 0; qt < 2; qt++)
#pragma unroll
    for (int ch = 0; ch < 2; ch++)
      qf[qt][ch] = *(const bf16x8*)(Qb + (size_t)(b * NSEQ + qb + qt * 16 + lq) * DIMV
                                    + h * DH + ch * 32 + g * 8);

  // all-ones bf16 A-fragment for the l "ones-column" MFMA
  bf16x8 onesf;
#pragma unroll
  for (int j = 0; j < 8; j++) onesf[j] = (short)0x3F80;

  // hoisted per-lane LDS byte offsets
  int koff[2], voff[2];
#pragma unroll
  for (int ch = 0; ch < 2; ch++)
    koff[ch] = lq * 128 + (((g ^ m) ^ (ch * 4)) << 4);
#pragma unroll
  for (int c = 0; c < 2; c++)
    voff[c] = lq * 128 + ((((4 * c + g)) ^ m) << 4);

  // hoisted staging source pointers (advance 1 KV-tile per stage)
  const unsigned short *pK0, *pK1, *pV0, *pV1;
  {
    int o0 = w * 1024 + lane * 16;
    int r0 = o0 >> 7, j0 = (o0 >> 4) & 7;
    pK0 = Kb + (size_t)(b * NSEQ + r0) * DIMV + h * DH + ((j0 ^ (r0 & 7)) << 3);
    pV0 = Vt + (size_t)(bh * DH + r0) * NSEQ + ((j0 ^ (r0 & 7)) << 3);
    int o1 = (4 + w) * 1024 + lane * 16;
    int r1 = o1 >> 7, j1 = (o1 >> 4) & 7;
    pK1 = Kb + (size_t)(b * NSEQ + r1) * DIMV + h * DH + ((j1 ^ (r1 & 7)) << 3);
    pV1 = Vt + (size_t)(bh * DH + r1) * NSEQ + ((j1 ^ (r1 & 7)) << 3);
  }

  f32x4 accO[2][4], accL[2];
  f32x4 zero = {0.f, 0.f, 0.f, 0.f};
#pragma unroll
  for (int qt = 0; qt < 2; qt++){
    accL[qt] = zero;
#pragma unroll
    for (int dt = 0; dt < 4; dt++) accO[qt][dt] = zero;
  }

  auto stage = [&](int buf){
    char* kb = (char*)Ks + buf * 8192 + w * 1024;
    char* vbp = (char*)Vs + buf * 8192 + w * 1024;
    gl16(pK0, kb);
    gl16(pK1, kb + 4096);
    gl16(pV0, vbp);
    gl16(pV1, vbp + 4096);
    pK0 += 64 * DIMV; pK1 += 64 * DIMV; pV0 += 64; pV1 += 64;
  };

  auto compute = [&](int base){
    const char* KB = (const char*)Ks + base;
    const char* VB = (const char*)Vs + base;
    bf16x8 kf[4][2];
#pragma unroll
    for (int t = 0; t < 4; t++)
#pragma unroll
      for (int ch = 0; ch < 2; ch++)
        kf[t][ch] = *(const bf16x8*)(KB + koff[ch] + t * 2048);

    // QK^T for both q-tiles as one MFMA cluster
    f32x4 st[2][4];
    __builtin_amdgcn_s_setprio(1);
#pragma unroll
    for (int qt = 0; qt < 2; qt++)
#pragma unroll
      for (int t = 0; t < 4; t++){
        f32x4 a = zero;
        a = __builtin_amdgcn_mfma_f32_16x16x32_bf16(kf[t][0], qf[qt][0], a, 0, 0, 0);
        a = __builtin_amdgcn_mfma_f32_16x16x32_bf16(kf[t][1], qf[qt][1], a, 0, 0, 0);
        st[qt][t] = a;
      }
    __builtin_amdgcn_s_setprio(0);

    // max-free softmax: P = exp2(S); l comes from the ones-MFMA below
    bf16x8 pa[2][2];
#pragma unroll
    for (int qt = 0; qt < 2; qt++){
#pragma unroll
      for (int t = 0; t < 4; t++)
#pragma unroll
        for (int r = 0; r < 4; r++)
          st[qt][t][r] = __builtin_amdgcn_exp2f(st[qt][t][r]);
#pragma unroll
      for (int c = 0; c < 2; c++){
        union { bf16x8 v; unsigned u[4]; } pu;
        pu.u[0] = cvt_pk_bf16(st[qt][2 * c][0], st[qt][2 * c][1]);
        pu.u[1] = cvt_pk_bf16(st[qt][2 * c][2], st[qt][2 * c][3]);
        pu.u[2] = cvt_pk_bf16(st[qt][2 * c + 1][0], st[qt][2 * c + 1][1]);
        pu.u[3] = cvt_pk_bf16(st[qt][2 * c + 1][2], st[qt][2 * c + 1][3]);
        pa[qt][c] = pu.v;
      }
    }

    // PV + l: A = V slots (kv-permuted) single b128 per (c,dt); ones-frag gives l
    __builtin_amdgcn_s_setprio(1);
#pragma unroll
    for (int c = 0; c < 2; c++){
#pragma unroll
      for (int qt = 0; qt < 2; qt++)
        accL[qt] = __builtin_amdgcn_mfma_f32_16x16x32_bf16(onesf, pa[qt][c], accL[qt], 0, 0, 0);
#pragma unroll
      for (int dt = 0; dt < 4; dt++){
        bf16x8 vfrag = *(const bf16x8*)(VB + voff[c] + dt * 2048);
#pragma unroll
        for (int qt = 0; qt < 2; qt++)
          accO[qt][dt] = __builtin_amdgcn_mfma_f32_16x16x32_bf16(vfrag, pa[qt][c], accO[qt][dt], 0, 0, 0);
      }
    }
    __builtin_amdgcn_s_setprio(0);
  };

  // 3-deep pipeline: buf p's loads land while buf p-1 computes; vmcnt(4) leaves
  // buf p+1's 4 loads in flight across the barrier. Safety: all ds_reads of
  // compute(p-1) completed before its MFMAs issued (compiler lgkmcnt), so after
  // the barrier buf (p+2)%3 == (p-1)%3 is dead and safe to overwrite.
  stage(0);
  stage(1);
  int cur = 0;
#pragma unroll 1
  for (int p = 0; p < NSEQ / 64; p++){
    if (p < NSEQ / 64 - 1) asm volatile("s_waitcnt vmcnt(4)" ::: "memory");
    else                   asm volatile("s_waitcnt vmcnt(0)" ::: "memory");
    __builtin_amdgcn_s_barrier();
    if (p < NSEQ / 64 - 2){
      int nxt = cur - 1; if (nxt < 0) nxt = 2;   // (cur+2)%3
      stage(nxt);
    }
    compute(cur * 8192);
    cur = (cur == 2) ? 0 : cur + 1;
  }

  // O = accO / l ; lane holds O^T[d = dt*16 + 4g + r][q = lq]; accL rows all = l[lq]
#pragma unroll
  for (int qt = 0; qt < 2; qt++){
    float inv = 1.0f / accL[qt][0];
    int grow = b * NSEQ + qb + qt * 16 + lq;
#pragma unroll
    for (int dt = 0; dt < 4; dt++){
      u16x4 pk;
#pragma unroll
      for (int r = 0; r < 4; r++) pk[r] = f2bf(accO[qt][dt][r] * inv);
      *(u16x4*)(Ob + (size_t)grow * DIMV + h * DH + dt * 16 + 4 * g) = pk;
    }
  }
}

// ---------------- out projection: out = Ob @ Wo + bo (f32 out) ----------------
// 128x192 tiles (grid 64x4 = 256 = exactly 1 block/CU).  (round-9 state)
__global__ __launch_bounds__(256, 3) void gemm_out_kernel(const unsigned short* __restrict__ Ob,
                                                          const unsigned short* __restrict__ Wot,
                                                          const float* __restrict__ bo,
                                                          float* __restrict__ out){
  int m0 = blockIdx.x * 128;
  int nb = blockIdx.y * 192;
  __shared__ __align__(16) unsigned short As[128 * 64];
  __shared__ __align__(16) unsigned short Bs[192 * 64];
  int tid = threadIdx.x;
  int wid = tid >> 6, lane = tid & 63;
  int wr = wid >> 1, wc = wid & 1;
  int q = lane >> 4, rr = lane & 15, m8 = rr & 7;

  f32x4 acc[4][6];
  f32x4 zero = {0.f, 0.f, 0.f, 0.f};
#pragma unroll
  for (int i = 0; i < 4; i++)
#pragma unroll
    for (int j = 0; j < 6; j++) acc[i][j] = zero;

  int aoff[2], boff[2];
#pragma unroll
  for (int kk = 0; kk < 2; kk++){
    int cx = (((kk * 4 + q) ^ m8) << 4);
    aoff[kk] = (wr * 64 + rr) * 128 + cx;
    boff[kk] = (wc * 96 + rr) * 128 + cx;
  }
  int srow = wid * 8 + (lane >> 3);
  int sjc = ((lane & 7) ^ ((lane >> 3) & 7)) << 3;
  const unsigned short* pA0 = Ob  + (size_t)(m0 + srow) * DIMV + sjc;
  const unsigned short* pB0 = Wot + (size_t)(nb + srow) * DIMV + sjc;

  auto stage = [&](){
#pragma unroll
    for (int rd = 0; rd < 4; rd++)
      gl16(pA0 + rd * 32 * DIMV, (char*)As + (rd * 4 + wid) * 1024);
#pragma unroll
    for (int i = 0; i < 6; i++)
      gl16(pB0 + i * 32 * DIMV, (char*)Bs + (i * 4 + wid) * 1024);
    pA0 += 64; pB0 += 64;
  };

  for (int kt = 0; kt < DIMV / 64; kt++){
    __syncthreads();
    stage();
    asm volatile("s_waitcnt vmcnt(0)" ::: "memory");
    __syncthreads();
#pragma unroll
    for (int kk = 0; kk < 2; kk++){
      bf16x8 af[4], bfm[6];
#pragma unroll
      for (int mi = 0; mi < 4; mi++)
        af[mi] = *(const bf16x8*)((char*)As + aoff[kk] + mi * 2048);
#pragma unroll
      for (int ni = 0; ni < 6; ni++)
        bfm[ni] = *(const bf16x8*)((char*)Bs + boff[kk] + ni * 2048);
      __builtin_amdgcn_s_setprio(1);
#pragma unroll
      for (int mi = 0; mi < 4; mi++)
#pragma unroll
        for (int ni = 0; ni < 6; ni++)
          acc[mi][ni] = __builtin_amdgcn_mfma_f32_16x16x32_bf16(af[mi], bfm[ni], acc[mi][ni], 0, 0, 0);
      __builtin_amdgcn_s_setprio(0);
    }
  }

#pragma unroll
  for (int mi = 0; mi < 4; mi++){
#pragma unroll
    for (int ni = 0; ni < 6; ni++){
      int col = nb + wc * 96 + ni * 16 + rr;
      int mrow0 = m0 + wr * 64 + mi * 16 + q * 4;
      float bias = bo[col];
      f32x4 v = acc[mi][ni];
#pragma unroll
      for (int r = 0; r < 4; r++)
        out[(size_t)(mrow0 + r) * DIMV + col] = v[r] + bias;
    }
  }
}

extern "C" void kernel_launch(void* const* d_in, const int* in_sizes, int n_in,
                              void* d_out, int out_size, void* d_ws, size_t ws_size,
                              hipStream_t stream){
  const float* x  = (const float*)d_in[0];
  const float* Wq = (const float*)d_in[1];
  const float* Wk = (const float*)d_in[2];
  const float* Wv = (const float*)d_in[3];
  const float* Wo = (const float*)d_in[4];
  const float* bo = (const float*)d_in[5];
  float* out = (float*)d_out;

  char* ws = (char*)d_ws;
  const size_t SZ_MAT = (size_t)MTOT * DIMV * 2;
  const size_t SZ_W   = (size_t)DIMV * DIMV * 2;
  unsigned short* Xb  = (unsigned short*)(ws);
  unsigned short* Wts = (unsigned short*)(ws + SZ_MAT);
  unsigned short* Qb  = (unsigned short*)(ws + SZ_MAT + 4 * SZ_W);
  unsigned short* Kb  = (unsigned short*)(ws + 2 * SZ_MAT + 4 * SZ_W);
  unsigned short* Vt  = (unsigned short*)(ws + 3 * SZ_MAT + 4 * SZ_W);
  unsigned short* Ob  = (unsigned short*)(ws + 4 * SZ_MAT + 4 * SZ_W);

  prep_kernel<<<dim3(3072 + 2304), dim3(256), 0, stream>>>(x, Wq, Wk, Wv, Wo, Xb, Wts);
  gemm_qkv_kernel<<<dim3(MTOT / 128, 12), dim3(256), 0, stream>>>(Xb, Wts, Qb, Kb, Vt);
  attn_kernel<<<dim3(768), dim3(256), 0, stream>>>(Qb, Kb, Vt, Ob);
  gemm_out_kernel<<<dim3(MTOT / 128, 4), dim3(256), 0, stream>>>(Ob, Wts + 3 * (size_t)DIMV * DIMV, bo, out);
}

// Round 13
// 117.447 us; speedup vs baseline: 1.0176x; 1.0176x over previous
//
#include <hip/hip_runtime.h>

#define HEADS 12
#define DH 64
#define NB 4
#define NSEQ 2048
#define DIMV 768
#define MTOT (NB*NSEQ)   // 8192

typedef __attribute__((ext_vector_type(8))) short bf16x8;
typedef __attribute__((ext_vector_type(4))) short bf16x4;
typedef __attribute__((ext_vector_type(4))) float f32x4;
typedef __attribute__((ext_vector_type(8))) float f32x8;
typedef __attribute__((ext_vector_type(8))) unsigned short u16x8;
typedef __attribute__((ext_vector_type(4))) unsigned short u16x4;

__device__ __forceinline__ unsigned short f2bf(float f){
  union { float f; unsigned u; } v; v.f = f;
  unsigned r = v.u + 0x7FFFu + ((v.u >> 16) & 1u);
  return (unsigned short)(r >> 16);
}

__device__ __forceinline__ unsigned cvt_pk_bf16(float lo, float hi){
  unsigned r;
  asm("v_cvt_pk_bf16_f32 %0, %1, %2" : "=v"(r) : "v"(lo), "v"(hi));
  return r;
}

// async global->LDS, 16B per lane; LDS dest = wave-uniform base + lane*16
__device__ __forceinline__ void gl16(const void* g, void* l){
  __builtin_amdgcn_global_load_lds(
      (const __attribute__((address_space(1))) unsigned int*)g,
      (__attribute__((address_space(3))) unsigned int*)l, 16, 0, 0);
}

// ---------------- prep: x -> bf16  AND  W -> Wt bf16 [n][k], fused ----------------
__global__ __launch_bounds__(256) void prep_kernel(const float* __restrict__ x,
                                                   const float* __restrict__ Wq,
                                                   const float* __restrict__ Wk,
                                                   const float* __restrict__ Wv,
                                                   const float* __restrict__ Wo,
                                                   unsigned short* __restrict__ xb,
                                                   unsigned short* __restrict__ dstAll){
  __shared__ float t[32][33];
  int bid = blockIdx.x;
  if (bid < 3072){
    int i = (bid * 256 + (int)threadIdx.x) * 8;
    f32x8 v = *(const f32x8*)(x + i);
    u16x8 o;
#pragma unroll
    for (int j = 0; j < 8; j++) o[j] = f2bf(v[j]);
    *(u16x8*)(xb + i) = o;
  } else {
    int wb = bid - 3072;                  // 0..2303
    int w = wb / 576, rem = wb % 576;
    int n0 = (rem / 24) * 32, k0 = (rem % 24) * 32;
    const float* src = (w == 0) ? Wq : (w == 1) ? Wk : (w == 2) ? Wv : Wo;
    unsigned short* dst = dstAll + (size_t)w * DIMV * DIMV;
    int tx = threadIdx.x & 31, ty = threadIdx.x >> 5;   // 32 x 8
#pragma unroll
    for (int i = 0; i < 4; i++){
      int kk = ty + i * 8;
      t[kk][tx] = src[(k0 + kk) * DIMV + n0 + tx];
    }
    __syncthreads();
#pragma unroll
    for (int i = 0; i < 4; i++){
      int nn = ty + i * 8;
      dst[(n0 + nn) * DIMV + k0 + tx] = f2bf(t[tx][nn]);
    }
  }
}

// ---------------- QKV GEMM: C[8192 x 2304] = Xb @ [Wq|Wk|Wv] ----------------
// 128x192x64 tiles (grid 64x12 = 768 = exactly 3 blocks/CU), single-buffered,
// 48 MFMA/wave/iter. 192 | 768 so each n-tile lies in one z.
__global__ __launch_bounds__(256, 3) void gemm_qkv_kernel(const unsigned short* __restrict__ Xb,
                                                          const unsigned short* __restrict__ Wts,
                                                          unsigned short* __restrict__ Qb,
                                                          unsigned short* __restrict__ Kb,
                                                          unsigned short* __restrict__ Vt){
  int m0 = blockIdx.x * 128;
  int n2 = blockIdx.y;                   // 0..11
  int z  = n2 >> 2;
  int nb = (n2 & 3) * 192;
  const unsigned short* W = Wts + (size_t)z * DIMV * DIMV;  // Wt[n][k]
  __shared__ __align__(16) unsigned short As[128 * 64];     // 16KB
  __shared__ __align__(16) unsigned short Bs[192 * 64];     // 24KB
  int tid = threadIdx.x;
  int wid = tid >> 6, lane = tid & 63;
  int wr = wid >> 1, wc = wid & 1;
  int q = lane >> 4, rr = lane & 15, m8 = rr & 7;

  f32x4 acc[4][6];
  f32x4 zero = {0.f, 0.f, 0.f, 0.f};
#pragma unroll
  for (int i = 0; i < 4; i++)
#pragma unroll
    for (int j = 0; j < 6; j++) acc[i][j] = zero;

  int aoff[2], boff[2];
#pragma unroll
  for (int kk = 0; kk < 2; kk++){
    int cx = (((kk * 4 + q) ^ m8) << 4);
    aoff[kk] = (wr * 64 + rr) * 128 + cx;
    boff[kk] = (wc * 96 + rr) * 128 + cx;
  }
  // single base pointers; per-load row stride is compile-time (32 rows = 49152B)
  int srow = wid * 8 + (lane >> 3);
  int sjc = ((lane & 7) ^ ((lane >> 3) & 7)) << 3;
  const unsigned short* pA0 = Xb + (size_t)(m0 + srow) * DIMV + sjc;
  const unsigned short* pB0 = W  + (size_t)(nb + srow) * DIMV + sjc;

  auto stage = [&](){
#pragma unroll
    for (int rd = 0; rd < 4; rd++)
      gl16(pA0 + rd * 32 * DIMV, (char*)As + (rd * 4 + wid) * 1024);
#pragma unroll
    for (int i = 0; i < 6; i++)
      gl16(pB0 + i * 32 * DIMV, (char*)Bs + (i * 4 + wid) * 1024);
    pA0 += 64; pB0 += 64;
  };

  for (int kt = 0; kt < DIMV / 64; kt++){
    __syncthreads();
    stage();
    asm volatile("s_waitcnt vmcnt(0)" ::: "memory");
    __syncthreads();
#pragma unroll
    for (int kk = 0; kk < 2; kk++){
      bf16x8 af[4], bfm[6];
#pragma unroll
      for (int mi = 0; mi < 4; mi++)
        af[mi] = *(const bf16x8*)((char*)As + aoff[kk] + mi * 2048);
#pragma unroll
      for (int ni = 0; ni < 6; ni++)
        bfm[ni] = *(const bf16x8*)((char*)Bs + boff[kk] + ni * 2048);
      __builtin_amdgcn_s_setprio(1);
#pragma unroll
      for (int mi = 0; mi < 4; mi++)
#pragma unroll
        for (int ni = 0; ni < 6; ni++)
          acc[mi][ni] = __builtin_amdgcn_mfma_f32_16x16x32_bf16(af[mi], bfm[ni], acc[mi][ni], 0, 0, 0);
      __builtin_amdgcn_s_setprio(0);
    }
  }

  const float QSCALE = 0.125f * 1.4426950408889634f;  // fold softmax scale + log2e into Q
#pragma unroll
  for (int mi = 0; mi < 4; mi++){
#pragma unroll
    for (int ni = 0; ni < 6; ni++){
      int col = nb + wc * 96 + ni * 16 + rr;
      int mrow0 = m0 + wr * 64 + mi * 16 + q * 4;
      f32x4 v = acc[mi][ni];
      if (z == 0){
#pragma unroll
        for (int r = 0; r < 4; r++)
          Qb[(size_t)(mrow0 + r) * DIMV + col] = f2bf(v[r] * QSCALE);
      } else if (z == 1){
#pragma unroll
        for (int r = 0; r < 4; r++)
          Kb[(size_t)(mrow0 + r) * DIMV + col] = f2bf(v[r]);
      } else {
        int b = mrow0 >> 11;
        int n = mrow0 & 2047;
        // kv-permutation within each 32-chunk: slot = 8g+j <-> kv = 4g+j (+16 for j>=4)
        int np = (n & ~31) | (((n >> 2) & 3) << 3) | ((n & 16) >> 2);
        int h = col >> 6, d = col & 63;
        u16x4 pk;
#pragma unroll
        for (int r = 0; r < 4; r++) pk[r] = f2bf(v[r]);
        *(u16x4*)(&Vt[(((size_t)b * HEADS + h) * DH + d) * NSEQ + np]) = pk;
      }
    }
  }
}

// ---------------- flash attention, swapped-QK^T, max-free log2 softmax ----------------
// 4 waves x 32 q-rows, KV tile 64, K/V dbuf in LDS, kv-permuted V (single-b128 PV
// reads), XCD head-locality. l computed ON THE MATRIX PIPE via all-ones A-fragment.
__global__ __launch_bounds__(256, 3) void attn_kernel(const unsigned short* __restrict__ Qb,
                                                      const unsigned short* __restrict__ Kb,
                                                      const unsigned short* __restrict__ Vt,
                                                      unsigned short* __restrict__ Ob){
  int bid = blockIdx.x;                  // 768 = 8 xcd * 6 heads * 16 qx
  int xcd = bid & 7, wi = bid >> 3;      // wi in [0,96)
  int bh = xcd * 6 + (wi >> 4);
  int qx = wi & 15;
  int b = bh / HEADS, h = bh % HEADS;
  int tid = threadIdx.x, w = tid >> 6, lane = tid & 63;
  int lq = lane & 15, g = lane >> 4, m = lq & 7;

  __shared__ __align__(16) unsigned short Ks[2][64 * 64];  // [kv][d], 16B-chunk XOR swizzle
  __shared__ __align__(16) unsigned short Vs[2][64 * 64];  // [d][kv-permuted], swizzled

  int qb = qx * 128 + w * 32;

  // Q^T B-fragments: lane holds Q[q=lq][d = ch*32 + 8g..+8]
  bf16x8 qf[2][2];
#pragma unroll
  for (int qt = 0; qt < 2; qt++)
#pragma unroll
    for (int ch = 0; ch < 2; ch++)
      qf[qt][ch] = *(const bf16x8*)(Qb + (size_t)(b * NSEQ + qb + qt * 16 + lq) * DIMV
                                    + h * DH + ch * 32 + g * 8);

  // all-ones bf16 A-fragment for the l "ones-column" MFMA
  bf16x8 onesf;
#pragma unroll
  for (int j = 0; j < 8; j++) onesf[j] = (short)0x3F80;

  // hoisted per-lane LDS byte offsets
  int koff[2], voff[2];
#pragma unroll
  for (int ch = 0; ch < 2; ch++)
    koff[ch] = lq * 128 + (((g ^ m) ^ (ch * 4)) << 4);
#pragma unroll
  for (int c = 0; c < 2; c++)
    voff[c] = lq * 128 + ((((4 * c + g)) ^ m) << 4);

  // hoisted staging source pointers (advance 1 KV-tile per stage)
  const unsigned short *pK0, *pK1, *pV0, *pV1;
  {
    int o0 = w * 1024 + lane * 16;
    int r0 = o0 >> 7, j0 = (o0 >> 4) & 7;
    pK0 = Kb + (size_t)(b * NSEQ + r0) * DIMV + h * DH + ((j0 ^ (r0 & 7)) << 3);
    pV0 = Vt + (size_t)(bh * DH + r0) * NSEQ + ((j0 ^ (r0 & 7)) << 3);
    int o1 = (4 + w) * 1024 + lane * 16;
    int r1 = o1 >> 7, j1 = (o1 >> 4) & 7;
    pK1 = Kb + (size_t)(b * NSEQ + r1) * DIMV + h * DH + ((j1 ^ (r1 & 7)) << 3);
    pV1 = Vt + (size_t)(bh * DH + r1) * NSEQ + ((j1 ^ (r1 & 7)) << 3);
  }

  f32x4 accO[2][4], accL[2];
  f32x4 zero = {0.f, 0.f, 0.f, 0.f};
#pragma unroll
  for (int qt = 0; qt < 2; qt++){
    accL[qt] = zero;
#pragma unroll
    for (int dt = 0; dt < 4; dt++) accO[qt][dt] = zero;
  }

  auto stage = [&](int BUF){
    char* kb = (char*)Ks + BUF * 8192 + w * 1024;
    char* vbp = (char*)Vs + BUF * 8192 + w * 1024;
    gl16(pK0, kb);
    gl16(pK1, kb + 4096);
    gl16(pV0, vbp);
    gl16(pV1, vbp + 4096);
    pK0 += 64 * DIMV; pK1 += 64 * DIMV; pV0 += 64; pV1 += 64;
  };

  auto compute = [&](int BUF){
    const char* KB = (const char*)Ks + BUF * 8192;
    const char* VB = (const char*)Vs + BUF * 8192;
    bf16x8 kf[4][2];
#pragma unroll
    for (int t = 0; t < 4; t++)
#pragma unroll
      for (int ch = 0; ch < 2; ch++)
        kf[t][ch] = *(const bf16x8*)(KB + koff[ch] + t * 2048);

    // QK^T for both q-tiles as one MFMA cluster
    f32x4 st[2][4];
    __builtin_amdgcn_s_setprio(1);
#pragma unroll
    for (int qt = 0; qt < 2; qt++)
#pragma unroll
      for (int t = 0; t < 4; t++){
        f32x4 a = zero;
        a = __builtin_amdgcn_mfma_f32_16x16x32_bf16(kf[t][0], qf[qt][0], a, 0, 0, 0);
        a = __builtin_amdgcn_mfma_f32_16x16x32_bf16(kf[t][1], qf[qt][1], a, 0, 0, 0);
        st[qt][t] = a;
      }
    __builtin_amdgcn_s_setprio(0);

    // max-free softmax: P = exp2(S); l comes from the ones-MFMA below
    bf16x8 pa[2][2];
#pragma unroll
    for (int qt = 0; qt < 2; qt++){
#pragma unroll
      for (int t = 0; t < 4; t++)
#pragma unroll
        for (int r = 0; r < 4; r++)
          st[qt][t][r] = __builtin_amdgcn_exp2f(st[qt][t][r]);
#pragma unroll
      for (int c = 0; c < 2; c++){
        union { bf16x8 v; unsigned u[4]; } pu;
        pu.u[0] = cvt_pk_bf16(st[qt][2 * c][0], st[qt][2 * c][1]);
        pu.u[1] = cvt_pk_bf16(st[qt][2 * c][2], st[qt][2 * c][3]);
        pu.u[2] = cvt_pk_bf16(st[qt][2 * c + 1][0], st[qt][2 * c + 1][1]);
        pu.u[3] = cvt_pk_bf16(st[qt][2 * c + 1][2], st[qt][2 * c + 1][3]);
        pa[qt][c] = pu.v;
      }
    }

    // PV + l: A = V slots (kv-permuted) single b128 per (c,dt); ones-frag gives l
    __builtin_amdgcn_s_setprio(1);
#pragma unroll
    for (int c = 0; c < 2; c++){
#pragma unroll
      for (int qt = 0; qt < 2; qt++)
        accL[qt] = __builtin_amdgcn_mfma_f32_16x16x32_bf16(onesf, pa[qt][c], accL[qt], 0, 0, 0);
#pragma unroll
      for (int dt = 0; dt < 4; dt++){
        bf16x8 vfrag = *(const bf16x8*)(VB + voff[c] + dt * 2048);
#pragma unroll
        for (int qt = 0; qt < 2; qt++)
          accO[qt][dt] = __builtin_amdgcn_mfma_f32_16x16x32_bf16(vfrag, pa[qt][c], accO[qt][dt], 0, 0, 0);
      }
    }
    __builtin_amdgcn_s_setprio(0);
  };

  stage(0);
#pragma unroll 1
  for (int p = 0; p < NSEQ / 128; p++){
    asm volatile("s_waitcnt vmcnt(0)" ::: "memory");
    __syncthreads();
    stage(1);
    compute(0);
    asm volatile("s_waitcnt vmcnt(0)" ::: "memory");
    __syncthreads();
    if (p < NSEQ / 128 - 1) stage(0);
    compute(1);
  }

  // O = accO / l ; lane holds O^T[d = dt*16 + 4g + r][q = lq]; accL rows all = l[lq]
#pragma unroll
  for (int qt = 0; qt < 2; qt++){
    float inv = 1.0f / accL[qt][0];
    int grow = b * NSEQ + qb + qt * 16 + lq;
#pragma unroll
    for (int dt = 0; dt < 4; dt++){
      u16x4 pk;
#pragma unroll
      for (int r = 0; r < 4; r++) pk[r] = f2bf(accO[qt][dt][r] * inv);
      *(u16x4*)(Ob + (size_t)grow * DIMV + h * DH + dt * 16 + 4 * g) = pk;
    }
  }
}

// ---------------- out projection: out = Ob @ Wo + bo (f32 out) ----------------
// 128x192 tiles (grid 64x4 = 256 = exactly 1 block/CU).
__global__ __launch_bounds__(256, 3) void gemm_out_kernel(const unsigned short* __restrict__ Ob,
                                                          const unsigned short* __restrict__ Wot,
                                                          const float* __restrict__ bo,
                                                          float* __restrict__ out){
  int m0 = blockIdx.x * 128;
  int nb = blockIdx.y * 192;
  __shared__ __align__(16) unsigned short As[128 * 64];
  __shared__ __align__(16) unsigned short Bs[192 * 64];
  int tid = threadIdx.x;
  int wid = tid >> 6, lane = tid & 63;
  int wr = wid >> 1, wc = wid & 1;
  int q = lane >> 4, rr = lane & 15, m8 = rr & 7;

  f32x4 acc[4][6];
  f32x4 zero = {0.f, 0.f, 0.f, 0.f};
#pragma unroll
  for (int i = 0; i < 4; i++)
#pragma unroll
    for (int j = 0; j < 6; j++) acc[i][j] = zero;

  int aoff[2], boff[2];
#pragma unroll
  for (int kk = 0; kk < 2; kk++){
    int cx = (((kk * 4 + q) ^ m8) << 4);
    aoff[kk] = (wr * 64 + rr) * 128 + cx;
    boff[kk] = (wc * 96 + rr) * 128 + cx;
  }
  int srow = wid * 8 + (lane >> 3);
  int sjc = ((lane & 7) ^ ((lane >> 3) & 7)) << 3;
  const unsigned short* pA0 = Ob  + (size_t)(m0 + srow) * DIMV + sjc;
  const unsigned short* pB0 = Wot + (size_t)(nb + srow) * DIMV + sjc;

  auto stage = [&](){
#pragma unroll
    for (int rd = 0; rd < 4; rd++)
      gl16(pA0 + rd * 32 * DIMV, (char*)As + (rd * 4 + wid) * 1024);
#pragma unroll
    for (int i = 0; i < 6; i++)
      gl16(pB0 + i * 32 * DIMV, (char*)Bs + (i * 4 + wid) * 1024);
    pA0 += 64; pB0 += 64;
  };

  for (int kt = 0; kt < DIMV / 64; kt++){
    __syncthreads();
    stage();
    asm volatile("s_waitcnt vmcnt(0)" ::: "memory");
    __syncthreads();
#pragma unroll
    for (int kk = 0; kk < 2; kk++){
      bf16x8 af[4], bfm[6];
#pragma unroll
      for (int mi = 0; mi < 4; mi++)
        af[mi] = *(const bf16x8*)((char*)As + aoff[kk] + mi * 2048);
#pragma unroll
      for (int ni = 0; ni < 6; ni++)
        bfm[ni] = *(const bf16x8*)((char*)Bs + boff[kk] + ni * 2048);
      __builtin_amdgcn_s_setprio(1);
#pragma unroll
      for (int mi = 0; mi < 4; mi++)
#pragma unroll
        for (int ni = 0; ni < 6; ni++)
          acc[mi][ni] = __builtin_amdgcn_mfma_f32_16x16x32_bf16(af[mi], bfm[ni], acc[mi][ni], 0, 0, 0);
      __builtin_amdgcn_s_setprio(0);
    }
  }

#pragma unroll
  for (int mi = 0; mi < 4; mi++){
#pragma unroll
    for (int ni = 0; ni < 6; ni++){
      int col = nb + wc * 96 + ni * 16 + rr;
      int mrow0 = m0 + wr * 64 + mi * 16 + q * 4;
      float bias = bo[col];
      f32x4 v = acc[mi][ni];
#pragma unroll
      for (int r = 0; r < 4; r++)
        out[(size_t)(mrow0 + r) * DIMV + col] = v[r] + bias;
    }
  }
}

extern "C" void kernel_launch(void* const* d_in, const int* in_sizes, int n_in,
                              void* d_out, int out_size, void* d_ws, size_t ws_size,
                              hipStream_t stream){
  const float* x  = (const float*)d_in[0];
  const float* Wq = (const float*)d_in[1];
  const float* Wk = (const float*)d_in[2];
  const float* Wv = (const float*)d_in[3];
  const float* Wo = (const float*)d_in[4];
  const float* bo = (const float*)d_in[5];
  float* out = (float*)d_out;

  char* ws = (char*)d_ws;
  const size_t SZ_MAT = (size_t)MTOT * DIMV * 2;
  const size_t SZ_W   = (size_t)DIMV * DIMV * 2;
  unsigned short* Xb  = (unsigned short*)(ws);
  unsigned short* Wts = (unsigned short*)(ws + SZ_MAT);
  unsigned short* Qb  = (unsigned short*)(ws + SZ_MAT + 4 * SZ_W);
  unsigned short* Kb  = (unsigned short*)(ws + 2 * SZ_MAT + 4 * SZ_W);
  unsigned short* Vt  = (unsigned short*)(ws + 3 * SZ_MAT + 4 * SZ_W);
  unsigned short* Ob  = (unsigned short*)(ws + 4 * SZ_MAT + 4 * SZ_W);

  prep_kernel<<<dim3(3072 + 2304), dim3(256), 0, stream>>>(x, Wq, Wk, Wv, Wo, Xb, Wts);
  gemm_qkv_kernel<<<dim3(MTOT / 128, 12), dim3(256), 0, stream>>>(Xb, Wts, Qb, Kb, Vt);
  attn_kernel<<<dim3(768), dim3(256), 0, stream>>>(Qb, Kb, Vt, Ob);
  gemm_out_kernel<<<dim3(MTOT / 128, 4), dim3(256), 0, stream>>>(Ob, Wts + 3 * (size_t)DIMV * DIMV, bo, out);
}